// Round 1
// 841.065 us; speedup vs baseline: 1.0480x; 1.0480x over previous
//
#include <hip/hip_runtime.h>
#include <hip/hip_bf16.h>
#include <cstdio>

// Problem constants (S6HistoryCompressor)
#define S_LEN 2048
#define BATCH 16
#define D_INP 1024
#define H_DIM 2048
#define SC    (S_LEN / 2)       // compressed length (step=2, rows 1,3,...,2047)
#define BH    (BATCH * H_DIM)   // 32768 independent recurrences
#define NC    16                // scan chunks
#define CS    (S_LEN / NC)      // 128 steps per chunk

typedef __bf16 b16;
typedef __bf16 b16x8 __attribute__((ext_vector_type(8)));
typedef __bf16 b16x4 __attribute__((ext_vector_type(4)));
typedef float  f32x4 __attribute__((ext_vector_type(4)));

// XOR swizzle for LDS tile [R rows][32 bf16 cols], 16B granules.
// Physical slot p in row r holds LOGICAL granule p ^ ((r>>1)&3).
// Frag reads hit 2-way (free) bank aliasing only (even/odd rows split banks).
__device__ __forceinline__ int sw_off(int r, int k8) {
  return r * 32 + ((k8 ^ ((r >> 1) & 3)) << 3);
}

// Async global -> LDS, 16 B per lane. LDS dest = wave-uniform base + lane*16
// (hardware rule, m104/m108); swizzle is applied on the GLOBAL address side.
__device__ __forceinline__ void gl2lds16(const b16* g, b16* l) {
  __builtin_amdgcn_global_load_lds(
      (const __attribute__((address_space(1))) void*)g,
      (__attribute__((address_space(3))) void*)l, 16, 0, 0);
}

// Fast branchless softplus: log(1+e^t) = max(t,0) + log(1+e^-|t|).
__device__ __forceinline__ float softplus_fast(float t) {
  float e = __expf(-fabsf(t));
  return fmaxf(t, 0.f) + __logf(1.f + e);
}

// ---------------------------------------------------------------------------
// Conversions
// ---------------------------------------------------------------------------
__global__ void cvt_x_kernel(const float* __restrict__ in, b16* __restrict__ out, int n4) {
  int i = blockIdx.x * 256 + threadIdx.x;
  if (i >= n4) return;
  float4 v = ((const float4*)in)[i];
  b16x4 o = {(b16)v.x, (b16)v.y, (b16)v.z, (b16)v.w};
  ((b16x4*)out)[i] = o;
}

__global__ void prep_w_kernel(const float* __restrict__ Wd, const float* __restrict__ Win,
                              const float* __restrict__ WB, const float* __restrict__ Wc,
                              const float* __restrict__ Wcp,
                              b16* __restrict__ Wdu, b16* __restrict__ Wcb,
                              b16* __restrict__ Wcpb) {
  const int HD4 = (H_DIM * D_INP) / 4;
  int i = blockIdx.x * 256 + threadIdx.x;
  if (i >= HD4) return;
  float4 a = ((const float4*)Wd)[i];
  float4 b = ((const float4*)Win)[i];
  float4 c = ((const float4*)WB)[i];
  float4 d = ((const float4*)Wc)[i];
  float4 e = ((const float4*)Wcp)[i];
  ((b16x4*)Wdu)[i] = {(b16)a.x, (b16)a.y, (b16)a.z, (b16)a.w};
  ((b16x4*)Wdu)[HD4 + i] = {(b16)(b.x + c.x), (b16)(b.y + c.y), (b16)(b.z + c.z), (b16)(b.w + c.w)};
  ((b16x4*)Wcb)[i] = {(b16)d.x, (b16)d.y, (b16)d.z, (b16)d.w};
  ((b16x4*)Wcpb)[i] = {(b16)e.x, (b16)e.y, (b16)e.z, (b16)e.w};
}

// ---------------------------------------------------------------------------
// 256x256 deep-pipelined GEMM: C[M,N] = A[M,K] (bf16 rm) x W[N,K]^T (bf16 rm)
// 8 waves (512 thr), per-wave 128x64 (acc[8][4]), BK=32, 4-deep LDS ring
// (128 KB dynamic), counted vmcnt across raw s_barrier (T4), setprio (T5),
// XCD-swizzled block id (T1).
//
// Pipeline (per wave, 4 global_load_lds per tile):
//   prologue: stage(0..2)
//   iter t:  vmcnt(8)  -> tile t landed (t+1,t+2 stay in flight)
//            s_barrier -> all waves' tile-t data visible; all waves done
//                         reading buf[(t-1)&3]  => stage(t+3) region-safe
//            stage(t+3) into buf[(t+3)&3]
//            ds_read 12 frags from buf[t&3]; 32 MFMA
//   tail: vmcnt(4), vmcnt(0) peels.
// ---------------------------------------------------------------------------
template <int MODE>
__device__ __forceinline__ void stage256(const b16* __restrict__ A, const b16* __restrict__ W,
                                         int K, int k0, b16* buf, int m0, int n0,
                                         int wave, int lane) {
  const int w = wave & 3;          // 4 waves stage A, 4 stage B
  const bool isB = wave >= 4;
  const int rr = lane >> 2;        // row within 16-row stripe
  const int gp = lane & 3;         // physical 16B granule
#pragma unroll
  for (int l = 0; l < 4; ++l) {
    const int rbase = w * 64 + l * 16;
    const int r = rbase + rr;                 // tile-local row 0..255
    const int gl = gp ^ ((r >> 1) & 3);       // logical granule to fetch
    b16* dst = buf + (isB ? 256 * 32 : 0) + rbase * 32;  // wave-uniform base
    const b16* src;
    if (isB) {
      src = W + (long)(n0 + r) * K + k0 + gl * 8;
    } else {
      long arow = m0 + r;
      if (MODE == 1) arow = 2 * arow - (arow & 15) + 16;  // odd-timestep remap
      src = A + arow * (long)K + k0 + gl * 8;
    }
    gl2lds16(src, dst);
  }
}

template <int MODE>
__global__ __launch_bounds__(512, 2) void gemm256(
    const b16* __restrict__ A, const b16* __restrict__ W, int K,
    const float* __restrict__ bias0, const float* __restrict__ bias1,
    const b16* __restrict__ hsel, b16* __restrict__ ob0, b16* __restrict__ ob1,
    float* __restrict__ of) {
  extern __shared__ b16 lds[];  // 4 bufs x (A 256x32 + B 256x32) = 128 KB
  const int tid  = threadIdx.x;
  const int lane = tid & 63;
  const int wave = tid >> 6;
  const int wm = wave >> 2, wn = wave & 3;
  const int lm = lane & 15;
  const int l8 = lane >> 4;

  // Bijective XCD swizzle (all grids have nwg % 8 == 0): XCD k gets a
  // contiguous chunk of swizzled ids -> consecutive tiles share the A panel.
  const int gx  = gridDim.x;
  const int nwg = gx * gridDim.y;
  const int id0 = blockIdx.y * gx + blockIdx.x;
  const int sw  = (id0 & 7) * (nwg >> 3) + (id0 >> 3);
  const int m0 = (sw / gx) * 256;
  const int n0 = (sw % gx) * 256;

  f32x4 acc[8][4];
#pragma unroll
  for (int i = 0; i < 8; i++)
#pragma unroll
    for (int j = 0; j < 4; j++) acc[i][j] = (f32x4)0.f;

  const int NT = K >> 5;  // BK=32
  stage256<MODE>(A, W, K, 0,  lds + 0 * 16384, m0, n0, wave, lane);
  stage256<MODE>(A, W, K, 32, lds + 1 * 16384, m0, n0, wave, lane);
  stage256<MODE>(A, W, K, 64, lds + 2 * 16384, m0, n0, wave, lane);

  for (int t = 0; t < NT; ++t) {
    // Counted wait: tile t landed; newer stages stay in flight (never drain
    // to 0 in steady state -- the T4 lever).
    if (t + 2 < NT)      asm volatile("s_waitcnt vmcnt(8)" ::: "memory");
    else if (t + 1 < NT) asm volatile("s_waitcnt vmcnt(4)" ::: "memory");
    else                 asm volatile("s_waitcnt vmcnt(0)" ::: "memory");
    __builtin_amdgcn_s_barrier();
    if (t + 3 < NT)
      stage256<MODE>(A, W, K, (t + 3) << 5, lds + (size_t)((t + 3) & 3) * 16384,
                     m0, n0, wave, lane);
    const b16* As = lds + (size_t)(t & 3) * 16384;
    const b16* Bs = As + 256 * 32;
    b16x8 af[8], bfr[4];
#pragma unroll
    for (int i = 0; i < 8; i++) af[i] = *(const b16x8*)(As + sw_off(wm * 128 + i * 16 + lm, l8));
#pragma unroll
    for (int j = 0; j < 4; j++) bfr[j] = *(const b16x8*)(Bs + sw_off(wn * 64 + j * 16 + lm, l8));
    __builtin_amdgcn_s_setprio(1);
#pragma unroll
    for (int i = 0; i < 8; i++)
#pragma unroll
      for (int j = 0; j < 4; j++)
        acc[i][j] = __builtin_amdgcn_mfma_f32_16x16x32_bf16(af[i], bfr[j], acc[i][j], 0, 0, 0);
    __builtin_amdgcn_s_setprio(0);
  }

  // Epilogue. C/D layout: col = lane&15, row = (lane>>4)*4 + reg [m89/m91].
  if (MODE == 0) {
    const bool is_delta = (n0 < H_DIM);  // block-uniform (gx=16, 8+8 split)
    const float* bias = is_delta ? bias0 : bias1;
    b16* ob = is_delta ? ob0 : ob1;
    const int nc0 = (n0 & (H_DIM - 1)) + wn * 64 + lm;
    float bv[4];
#pragma unroll
    for (int j = 0; j < 4; j++) bv[j] = bias[nc0 + j * 16];
#pragma unroll
    for (int i = 0; i < 8; i++) {
      const long rb = m0 + wm * 128 + i * 16 + l8 * 4;
      b16* pr = ob + rb * H_DIM + nc0;
      if (is_delta) {
#pragma unroll
        for (int j = 0; j < 4; j++)
#pragma unroll
          for (int rg = 0; rg < 4; ++rg)
            pr[(long)rg * H_DIM + j * 16] = (b16)softplus_fast(acc[i][j][rg] + bv[j]);
      } else {
#pragma unroll
        for (int j = 0; j < 4; j++)
#pragma unroll
          for (int rg = 0; rg < 4; ++rg)
            pr[(long)rg * H_DIM + j * 16] = (b16)(acc[i][j][rg] + bv[j]);
      }
    }
  } else if (MODE == 1) {
    const int nc0 = n0 + wn * 64 + lm;
#pragma unroll
    for (int i = 0; i < 8; i++) {
      const long rb = m0 + wm * 128 + i * 16 + l8 * 4;
      const b16* hp = hsel + rb * H_DIM + nc0;
      b16* pr = ob0 + rb * H_DIM + nc0;
#pragma unroll
      for (int j = 0; j < 4; j++)
#pragma unroll
        for (int rg = 0; rg < 4; ++rg) {
          float hv = (float)hp[(long)rg * H_DIM + j * 16];
          pr[(long)rg * H_DIM + j * 16] = (b16)(acc[i][j][rg] * hv);
        }
    }
  } else {
    const int nc0 = n0 + wn * 64 + lm;
    float bv[4];
#pragma unroll
    for (int j = 0; j < 4; j++) bv[j] = bias0[nc0 + j * 16];
#pragma unroll
    for (int i = 0; i < 8; i++) {
      const long rb = m0 + wm * 128 + i * 16 + l8 * 4;
      float* pr = of + rb * D_INP + nc0;
#pragma unroll
      for (int j = 0; j < 4; j++)
#pragma unroll
        for (int rg = 0; rg < 4; ++rg)
          pr[(long)rg * D_INP + j * 16] = acc[i][j][rg] + bv[j];
    }
  }
}

// ---------------------------------------------------------------------------
// Fallback: previous 128x128 kernel (used only if 128 KB dynamic LDS opt-in
// is refused by the runtime).
// ---------------------------------------------------------------------------
template <int MODE>
__global__ __launch_bounds__(256, 2) void gemm_bt(
    const b16* __restrict__ A, const b16* __restrict__ W, int K,
    const float* __restrict__ bias0, const float* __restrict__ bias1,
    const b16* __restrict__ hsel, b16* __restrict__ ob0, b16* __restrict__ ob1,
    float* __restrict__ of) {
  __shared__ b16 As[128 * 32];
  __shared__ b16 Bs[128 * 32];
  const int tid  = threadIdx.x;
  const int lane = tid & 63;
  const int wave = tid >> 6;
  const int wr = wave >> 1, wc = wave & 1;
  const int m0 = blockIdx.y * 128;
  const int n0 = blockIdx.x * 128;
  const int lm = lane & 15;
  const int l8 = lane >> 4;
  const int rL  = wave * 16 + (lane >> 2);
  const int k8p = lane & 3;

  f32x4 acc[4][4];
#pragma unroll
  for (int i = 0; i < 4; i++)
#pragma unroll
    for (int j = 0; j < 4; j++) acc[i][j] = (f32x4)0.f;

  for (int k0 = 0; k0 < K; k0 += 32) {
#pragma unroll
    for (int hh = 0; hh < 2; ++hh) {
      const int r = rL + hh * 64;
      const int k8l = k8p ^ ((r >> 1) & 3);
      b16* ldsA = As + (wave * 16 + hh * 64) * 32;
      b16* ldsB = Bs + (wave * 16 + hh * 64) * 32;
      long arow = m0 + r;
      if (MODE == 1) arow = 2 * arow - (arow & 15) + 16;
      gl2lds16(A + arow * (long)K + k0 + k8l * 8, ldsA);
      gl2lds16(W + (long)(n0 + r) * K + k0 + k8l * 8, ldsB);
    }
    __syncthreads();
    b16x8 af[4], bfr[4];
#pragma unroll
    for (int i = 0; i < 4; i++) af[i] = *(const b16x8*)(As + sw_off(wr * 64 + i * 16 + lm, l8));
#pragma unroll
    for (int j = 0; j < 4; j++) bfr[j] = *(const b16x8*)(Bs + sw_off(wc * 64 + j * 16 + lm, l8));
#pragma unroll
    for (int i = 0; i < 4; i++)
#pragma unroll
      for (int j = 0; j < 4; j++)
        acc[i][j] = __builtin_amdgcn_mfma_f32_16x16x32_bf16(af[i], bfr[j], acc[i][j], 0, 0, 0);
    __syncthreads();
  }

  if (MODE == 0) {
    const bool is_delta = (n0 < H_DIM);
    const float* bias = is_delta ? bias0 : bias1;
    b16* ob = is_delta ? ob0 : ob1;
    const int nc0 = (n0 & (H_DIM - 1)) + wc * 64 + lm;
    float bv[4];
#pragma unroll
    for (int j = 0; j < 4; j++) bv[j] = bias[nc0 + j * 16];
#pragma unroll
    for (int i = 0; i < 4; i++) {
      const long rb = m0 + wr * 64 + i * 16 + l8 * 4;
      b16* pr = ob + rb * H_DIM + nc0;
      if (is_delta) {
#pragma unroll
        for (int j = 0; j < 4; j++)
#pragma unroll
          for (int rg = 0; rg < 4; ++rg)
            pr[(long)rg * H_DIM + j * 16] = (b16)softplus_fast(acc[i][j][rg] + bv[j]);
      } else {
#pragma unroll
        for (int j = 0; j < 4; j++)
#pragma unroll
          for (int rg = 0; rg < 4; ++rg)
            pr[(long)rg * H_DIM + j * 16] = (b16)(acc[i][j][rg] + bv[j]);
      }
    }
  } else if (MODE == 1) {
    const int nc0 = n0 + wc * 64 + lm;
#pragma unroll
    for (int i = 0; i < 4; i++) {
      const long rb = m0 + wr * 64 + i * 16 + l8 * 4;
      const b16* hp = hsel + rb * H_DIM + nc0;
      b16* pr = ob0 + rb * H_DIM + nc0;
#pragma unroll
      for (int j = 0; j < 4; j++)
#pragma unroll
        for (int rg = 0; rg < 4; ++rg) {
          float hv = (float)hp[(long)rg * H_DIM + j * 16];
          pr[(long)rg * H_DIM + j * 16] = (b16)(acc[i][j][rg] * hv);
        }
    }
  } else {
    const int nc0 = n0 + wc * 64 + lm;
    float bv[4];
#pragma unroll
    for (int j = 0; j < 4; j++) bv[j] = bias0[nc0 + j * 16];
#pragma unroll
    for (int i = 0; i < 4; i++) {
      const long rb = m0 + wr * 64 + i * 16 + l8 * 4;
      float* pr = of + rb * D_INP + nc0;
#pragma unroll
      for (int j = 0; j < 4; j++)
#pragma unroll
        for (int rg = 0; rg < 4; ++rg)
          pr[(long)rg * D_INP + j * 16] = acc[i][j][rg] + bv[j];
    }
  }
}

// ---------------------------------------------------------------------------
// Chunked-scan recurrence: h_t = (1-d_t) h_{t-1} + d_t u_t  (elementwise B*H)
// ---------------------------------------------------------------------------
__global__ void scan_a_kernel(const b16* __restrict__ dl, const b16* __restrict__ uu,
                              float* __restrict__ P, float* __restrict__ Q) {
  int g = blockIdx.x * 256 + threadIdx.x;
  int c = g >> 15;
  int p = g & (BH - 1);
  const b16* dp = dl + (size_t)c * CS * BH + p;
  const b16* up = uu + (size_t)c * CS * BH + p;
  float h = 0.f, pr = 1.f;
#pragma unroll 4
  for (int s = 0; s < CS; ++s) {
    float d = (float)dp[(size_t)s * BH];
    float u = (float)up[(size_t)s * BH];
    float a = 1.f - d;
    h = a * h + d * u;
    pr *= a;
  }
  P[g] = pr;
  Q[g] = h;
}

__global__ void scan_b_kernel(const float* __restrict__ P, const float* __restrict__ Q,
                              float* __restrict__ Hs) {
  int p = blockIdx.x * 256 + threadIdx.x;
  float h = 0.f;
#pragma unroll
  for (int c = 0; c < NC; ++c) {
    Hs[c * BH + p] = h;
    h = P[c * BH + p] * h + Q[c * BH + p];
  }
}

__global__ void scan_c_kernel(const b16* __restrict__ dl, const b16* __restrict__ uu,
                              const float* __restrict__ Hs, b16* __restrict__ hsel) {
  int g = blockIdx.x * 256 + threadIdx.x;
  int c = g >> 15;
  int p = g & (BH - 1);
  const b16* dp = dl + (size_t)c * CS * BH + p;
  const b16* up = uu + (size_t)c * CS * BH + p;
  b16* hp = hsel + (size_t)(c * (CS / 2)) * BH + p;
  float h = Hs[g];
#pragma unroll 4
  for (int s = 0; s < CS; ++s) {
    float d = (float)dp[(size_t)s * BH];
    float u = (float)up[(size_t)s * BH];
    h = (1.f - d) * h + d * u;
    if (s & 1) hp[(size_t)(s >> 1) * BH] = (b16)h;
  }
}

// ---------------------------------------------------------------------------
extern "C" void kernel_launch(void* const* d_in, const int* in_sizes, int n_in,
                              void* d_out, int out_size, void* d_ws, size_t ws_size,
                              hipStream_t stream) {
  const float* x   = (const float*)d_in[0];
  // d_in[1] = A (unused by the reference forward)
  const float* WB  = (const float*)d_in[2];
  const float* Wc  = (const float*)d_in[3];
  const float* Wd  = (const float*)d_in[4];
  const float* bd  = (const float*)d_in[5];
  const float* Win = (const float*)d_in[6];
  const float* bi  = (const float*)d_in[7];
  const float* Wcp = (const float*)d_in[8];
  const float* bc  = (const float*)d_in[9];
  float* out = (float*)d_out;

  char* w = (char*)d_ws;
  size_t off = 0;
  auto alloc = [&](size_t bytes) {
    void* p = w + off;
    off += (bytes + 255) & ~(size_t)255;
    return p;
  };
  b16* xb   = (b16*)alloc((size_t)S_LEN * BATCH * D_INP * 2);
  b16* Wdu  = (b16*)alloc((size_t)2 * H_DIM * D_INP * 2);
  b16* Wcb  = (b16*)alloc((size_t)H_DIM * D_INP * 2);
  b16* Wcpb = (b16*)alloc((size_t)D_INP * H_DIM * 2);
  b16* dbuf = (b16*)alloc((size_t)S_LEN * BH * 2);
  b16* ubuf = (b16*)alloc((size_t)S_LEN * BH * 2);
  b16* hsel = (b16*)alloc((size_t)SC * BH * 2);
  b16* ysel = (b16*)alloc((size_t)SC * BH * 2);
  float* P  = (float*)alloc((size_t)NC * BH * 4);
  float* Q  = (float*)alloc((size_t)NC * BH * 4);
  float* Hs = (float*)alloc((size_t)NC * BH * 4);
  if (off > ws_size) {
    fprintf(stderr, "kernel_launch: ws too small: need %zu have %zu\n", off, ws_size);
    return;
  }

  // One-time opt-in to 128 KB dynamic LDS for the 256x256 kernels.
  static int g_big = -1;
  if (g_big < 0) {
    hipError_t e0 = hipFuncSetAttribute(reinterpret_cast<const void*>(&gemm256<0>),
                                        hipFuncAttributeMaxDynamicSharedMemorySize, 131072);
    hipError_t e1 = hipFuncSetAttribute(reinterpret_cast<const void*>(&gemm256<1>),
                                        hipFuncAttributeMaxDynamicSharedMemorySize, 131072);
    hipError_t e2 = hipFuncSetAttribute(reinterpret_cast<const void*>(&gemm256<2>),
                                        hipFuncAttributeMaxDynamicSharedMemorySize, 131072);
    g_big = (e0 == hipSuccess && e1 == hipSuccess && e2 == hipSuccess) ? 1 : 0;
  }

  // 1) x -> bf16
  int n4 = S_LEN * BATCH * D_INP / 4;
  cvt_x_kernel<<<(n4 + 255) / 256, 256, 0, stream>>>(x, xb, n4);
  // 2) weights -> bf16 (+ W_in+W_B fold)
  int hd4 = H_DIM * D_INP / 4;
  prep_w_kernel<<<(hd4 + 255) / 256, 256, 0, stream>>>(Wd, Win, WB, Wc, Wcp, Wdu, Wcb, Wcpb);
  // 3) delta/u projections: M=32768, N=4096, K=1024
  if (g_big) {
    dim3 g1(2 * H_DIM / 256, S_LEN * BATCH / 256);  // 16 x 128 = 2048 blocks
    gemm256<0><<<g1, 512, 131072, stream>>>(xb, Wdu, D_INP, bd, bi, nullptr, dbuf, ubuf, nullptr);
  } else {
    dim3 g1(2 * H_DIM / 128, S_LEN * BATCH / 128);
    gemm_bt<0><<<g1, 256, 0, stream>>>(xb, Wdu, D_INP, bd, bi, nullptr, dbuf, ubuf, nullptr);
  }
  // 4-6) chunked scan over S
  scan_a_kernel<<<NC * BH / 256, 256, 0, stream>>>(dbuf, ubuf, P, Q);
  scan_b_kernel<<<BH / 256, 256, 0, stream>>>(P, Q, Hs);
  scan_c_kernel<<<NC * BH / 256, 256, 0, stream>>>(dbuf, ubuf, Hs, hsel);
  // 7) C projection at odd timesteps, fused *h: M=16384, N=2048, K=1024
  if (g_big) {
    dim3 g2(H_DIM / 256, SC * BATCH / 256);  // 8 x 64 = 512 blocks
    gemm256<1><<<g2, 512, 131072, stream>>>(xb, Wcb, D_INP, nullptr, nullptr, hsel, ysel, nullptr, nullptr);
  } else {
    dim3 g2(H_DIM / 128, SC * BATCH / 128);
    gemm_bt<1><<<g2, 256, 0, stream>>>(xb, Wcb, D_INP, nullptr, nullptr, hsel, ysel, nullptr, nullptr);
  }
  // 8) compress: M=16384, N=1024, K=2048, fp32 out + b_comp
  if (g_big) {
    dim3 g3(D_INP / 256, SC * BATCH / 256);  // 4 x 64 = 256 blocks
    gemm256<2><<<g3, 512, 131072, stream>>>(ysel, Wcpb, H_DIM, bc, nullptr, nullptr, nullptr, nullptr, out);
  } else {
    dim3 g3(D_INP / 128, SC * BATCH / 128);
    gemm_bt<2><<<g3, 256, 0, stream>>>(ysel, Wcpb, H_DIM, bc, nullptr, nullptr, nullptr, nullptr, out);
  }
}

// Round 2
// 811.740 us; speedup vs baseline: 1.0858x; 1.0361x over previous
//
#include <hip/hip_runtime.h>
#include <hip/hip_bf16.h>
#include <cstdio>

// Problem constants (S6HistoryCompressor)
#define S_LEN 2048
#define BATCH 16
#define D_INP 1024
#define H_DIM 2048
#define SC    (S_LEN / 2)       // compressed length (step=2, rows 1,3,...,2047)
#define BH    (BATCH * H_DIM)   // 32768 independent recurrences
#define NC    16                // scan chunks
#define CS    (S_LEN / NC)      // 128 steps per chunk

typedef __bf16 b16;
typedef __bf16 b16x8 __attribute__((ext_vector_type(8)));
typedef __bf16 b16x4 __attribute__((ext_vector_type(4)));
typedef float  f32x4 __attribute__((ext_vector_type(4)));

// XOR swizzle for LDS sub-tile [256 rows][32 bf16 cols], 16B granules.
// Physical slot p in row r holds LOGICAL granule p ^ ((r>>1)&3).
// Frag reads (lanes 0-15 = rows, l8 = granule) hit 2-way (free) aliasing only.
__device__ __forceinline__ int sw_off(int r, int k8) {
  return r * 32 + ((k8 ^ ((r >> 1) & 3)) << 3);
}

// Async global -> LDS, 16 B per lane. LDS dest = wave-uniform base + lane*16
// (hardware rule, m104/m108); swizzle is applied on the GLOBAL address side.
__device__ __forceinline__ void gl2lds16(const b16* g, b16* l) {
  __builtin_amdgcn_global_load_lds(
      (const __attribute__((address_space(1))) void*)g,
      (__attribute__((address_space(3))) void*)l, 16, 0, 0);
}

// Fast branchless softplus: log(1+e^t) = max(t,0) + log(1+e^-|t|).
__device__ __forceinline__ float softplus_fast(float t) {
  float e = __expf(-fabsf(t));
  return fmaxf(t, 0.f) + __logf(1.f + e);
}

// ---------------------------------------------------------------------------
// Conversions
// ---------------------------------------------------------------------------
__global__ void cvt_x_kernel(const float* __restrict__ in, b16* __restrict__ out, int n4) {
  int i = blockIdx.x * 256 + threadIdx.x;
  if (i >= n4) return;
  float4 v = ((const float4*)in)[i];
  b16x4 o = {(b16)v.x, (b16)v.y, (b16)v.z, (b16)v.w};
  ((b16x4*)out)[i] = o;
}

__global__ void prep_w_kernel(const float* __restrict__ Wd, const float* __restrict__ Win,
                              const float* __restrict__ WB, const float* __restrict__ Wc,
                              const float* __restrict__ Wcp,
                              b16* __restrict__ Wdu, b16* __restrict__ Wcb,
                              b16* __restrict__ Wcpb) {
  const int HD4 = (H_DIM * D_INP) / 4;
  int i = blockIdx.x * 256 + threadIdx.x;
  if (i >= HD4) return;
  float4 a = ((const float4*)Wd)[i];
  float4 b = ((const float4*)Win)[i];
  float4 c = ((const float4*)WB)[i];
  float4 d = ((const float4*)Wc)[i];
  float4 e = ((const float4*)Wcp)[i];
  ((b16x4*)Wdu)[i] = {(b16)a.x, (b16)a.y, (b16)a.z, (b16)a.w};
  ((b16x4*)Wdu)[HD4 + i] = {(b16)(b.x + c.x), (b16)(b.y + c.y), (b16)(b.z + c.z), (b16)(b.w + c.w)};
  ((b16x4*)Wcb)[i] = {(b16)d.x, (b16)d.y, (b16)d.z, (b16)d.w};
  ((b16x4*)Wcpb)[i] = {(b16)e.x, (b16)e.y, (b16)e.z, (b16)e.w};
}

// ---------------------------------------------------------------------------
// 8-phase 256x256 GEMM (m201 template port): C = A[M,K] x W[N,K]^T, bf16.
// 8 waves (512 thr), per-wave 128x64 (acc[8][4]), BK=64.
// LDS: 2 buffers x 64 KB; each buffer = Ah0|Ah1|Bh0|Bh1, four [256][32]
// swizzled k-half sub-tiles (16 KB each).
//
// Per K-tile t (4 phases), computing from buf[t&1], staging tile t+1 into
// buf[(t+1)&1]:
//   P0: read A(ks0) x8 + B(ks0,j01) x2 | stage Ah0(t+1) | bar;lgkm0;16 MFMA;bar
//   P1: read B(ks0,j23) x2             | stage Bh0(t+1) | vmcnt(4);bar;...;bar
//   P2: read A(ks1) x8 + B(ks1,j01) x2 | stage Ah1(t+1) | bar;...;bar
//   P3: read B(ks1,j23) x2             | stage Bh1(t+1) | vmcnt(4);bar;...;bar
// vmcnt(4) at P1 gates Ah1(t)/Bh1(t) (read in P2/P3); at P3 gates
// Ah0(t+1)/Bh0(t+1) (read in next P0). Each vmcnt precedes a barrier, so the
// per-wave wait becomes a collective guarantee. Never drains in steady state.
// ---------------------------------------------------------------------------
#define AH0 0
#define AH1 8192
#define BH0 16384
#define BH1 24576

template <int MODE>
__device__ __forceinline__ void stage_half(const b16* __restrict__ G, int ldg,
                                           int base_row, int kcol, b16* half_base,
                                           int wave, int lane, bool isA) {
#pragma unroll
  for (int q = 0; q < 2; ++q) {
    const int rbase = q * 128 + wave * 16;      // 16-row stripe (wave-uniform)
    const int r = rbase + (lane >> 2);          // row 0..255
    const int p = lane & 3;                     // physical granule
    const int gl = p ^ ((r >> 1) & 3);          // logical granule to fetch
    long grow = base_row + r;
    if (MODE == 1 && isA) grow = 2 * grow - (grow & 15) + 16;  // odd-t remap
    gl2lds16(G + grow * (long)ldg + kcol + gl * 8, half_base + rbase * 32);
  }
}

template <int MODE>
__global__ __launch_bounds__(512, 2) void gemm8p(
    const b16* __restrict__ A, const b16* __restrict__ W, int K,
    const float* __restrict__ bias0, const float* __restrict__ bias1,
    const b16* __restrict__ hsel, b16* __restrict__ ob0, b16* __restrict__ ob1,
    float* __restrict__ of) {
  extern __shared__ b16 lds[];  // 2 x 32768 b16 = 128 KB
  const int tid  = threadIdx.x;
  const int lane = tid & 63;
  const int wave = tid >> 6;
  const int wm = wave >> 2, wn = wave & 3;
  const int lm = lane & 15;
  const int l8 = lane >> 4;

  // Bijective XCD swizzle (all grids have nwg % 8 == 0): XCD k gets a
  // contiguous chunk of tiles -> consecutive same-XCD tiles share the A panel.
  const int gx  = gridDim.x;
  const int nwg = gx * gridDim.y;
  const int id0 = blockIdx.y * gx + blockIdx.x;
  const int sw  = (id0 & 7) * (nwg >> 3) + (id0 >> 3);
  const int m0 = (sw / gx) * 256;
  const int n0 = (sw % gx) * 256;

  f32x4 acc[8][4];
#pragma unroll
  for (int i = 0; i < 8; i++)
#pragma unroll
    for (int j = 0; j < 4; j++) acc[i][j] = (f32x4)0.f;

  const int NT = K >> 6;  // BK=64 tiles

  // Prologue: stage tile 0 (Ah0, Bh0 first -- they gate P0).
  {
    b16* B0 = lds;
    stage_half<MODE>(A, K, m0, 0,  B0 + AH0, wave, lane, true);
    stage_half<MODE>(W, K, n0, 0,  B0 + BH0, wave, lane, false);
    stage_half<MODE>(A, K, m0, 32, B0 + AH1, wave, lane, true);
    stage_half<MODE>(W, K, n0, 32, B0 + BH1, wave, lane, false);
    asm volatile("s_waitcnt vmcnt(4)" ::: "memory");  // Ah0,Bh0 landed
    __builtin_amdgcn_s_barrier();
  }

  for (int t = 0; t < NT; ++t) {
    b16* const C = lds + ((t & 1) << 15);
    b16* const N = lds + (((t + 1) & 1) << 15);
    const int kn = (t + 1) << 6;
    const bool pf = (t + 1 < NT);
    b16x8 a[8], bb0, bb1;

    // ---- P0: ks=0, j in {0,1} ------------------------------------------
#pragma unroll
    for (int i = 0; i < 8; i++)
      a[i] = *(const b16x8*)(C + AH0 + sw_off(wm * 128 + i * 16 + lm, l8));
    bb0 = *(const b16x8*)(C + BH0 + sw_off(wn * 64 + 0 + lm, l8));
    bb1 = *(const b16x8*)(C + BH0 + sw_off(wn * 64 + 16 + lm, l8));
    if (pf) stage_half<MODE>(A, K, m0, kn, N + AH0, wave, lane, true);
    __builtin_amdgcn_s_barrier();
    asm volatile("s_waitcnt lgkmcnt(0)" ::: "memory");
    __builtin_amdgcn_sched_barrier(0);
    __builtin_amdgcn_s_setprio(1);
#pragma unroll
    for (int i = 0; i < 8; i++) {
      acc[i][0] = __builtin_amdgcn_mfma_f32_16x16x32_bf16(a[i], bb0, acc[i][0], 0, 0, 0);
      acc[i][1] = __builtin_amdgcn_mfma_f32_16x16x32_bf16(a[i], bb1, acc[i][1], 0, 0, 0);
    }
    __builtin_amdgcn_s_setprio(0);
    __builtin_amdgcn_s_barrier();

    // ---- P1: ks=0, j in {2,3}; vmcnt gates Ah1(t)/Bh1(t) ----------------
    bb0 = *(const b16x8*)(C + BH0 + sw_off(wn * 64 + 32 + lm, l8));
    bb1 = *(const b16x8*)(C + BH0 + sw_off(wn * 64 + 48 + lm, l8));
    if (pf) {
      stage_half<MODE>(W, K, n0, kn, N + BH0, wave, lane, false);
      asm volatile("s_waitcnt vmcnt(4)" ::: "memory");
    } else {
      asm volatile("s_waitcnt vmcnt(0)" ::: "memory");
    }
    __builtin_amdgcn_s_barrier();
    asm volatile("s_waitcnt lgkmcnt(0)" ::: "memory");
    __builtin_amdgcn_sched_barrier(0);
    __builtin_amdgcn_s_setprio(1);
#pragma unroll
    for (int i = 0; i < 8; i++) {
      acc[i][2] = __builtin_amdgcn_mfma_f32_16x16x32_bf16(a[i], bb0, acc[i][2], 0, 0, 0);
      acc[i][3] = __builtin_amdgcn_mfma_f32_16x16x32_bf16(a[i], bb1, acc[i][3], 0, 0, 0);
    }
    __builtin_amdgcn_s_setprio(0);
    __builtin_amdgcn_s_barrier();

    // ---- P2: ks=1, j in {0,1} ------------------------------------------
#pragma unroll
    for (int i = 0; i < 8; i++)
      a[i] = *(const b16x8*)(C + AH1 + sw_off(wm * 128 + i * 16 + lm, l8));
    bb0 = *(const b16x8*)(C + BH1 + sw_off(wn * 64 + 0 + lm, l8));
    bb1 = *(const b16x8*)(C + BH1 + sw_off(wn * 64 + 16 + lm, l8));
    if (pf) stage_half<MODE>(A, K, m0, kn + 32, N + AH1, wave, lane, true);
    __builtin_amdgcn_s_barrier();
    asm volatile("s_waitcnt lgkmcnt(0)" ::: "memory");
    __builtin_amdgcn_sched_barrier(0);
    __builtin_amdgcn_s_setprio(1);
#pragma unroll
    for (int i = 0; i < 8; i++) {
      acc[i][0] = __builtin_amdgcn_mfma_f32_16x16x32_bf16(a[i], bb0, acc[i][0], 0, 0, 0);
      acc[i][1] = __builtin_amdgcn_mfma_f32_16x16x32_bf16(a[i], bb1, acc[i][1], 0, 0, 0);
    }
    __builtin_amdgcn_s_setprio(0);
    __builtin_amdgcn_s_barrier();

    // ---- P3: ks=1, j in {2,3}; vmcnt gates Ah0(t+1)/Bh0(t+1) ------------
    bb0 = *(const b16x8*)(C + BH1 + sw_off(wn * 64 + 32 + lm, l8));
    bb1 = *(const b16x8*)(C + BH1 + sw_off(wn * 64 + 48 + lm, l8));
    if (pf) {
      stage_half<MODE>(W, K, n0, kn + 32, N + BH1, wave, lane, false);
      asm volatile("s_waitcnt vmcnt(4)" ::: "memory");
    }
    __builtin_amdgcn_s_barrier();
    asm volatile("s_waitcnt lgkmcnt(0)" ::: "memory");
    __builtin_amdgcn_sched_barrier(0);
    __builtin_amdgcn_s_setprio(1);
#pragma unroll
    for (int i = 0; i < 8; i++) {
      acc[i][2] = __builtin_amdgcn_mfma_f32_16x16x32_bf16(a[i], bb0, acc[i][2], 0, 0, 0);
      acc[i][3] = __builtin_amdgcn_mfma_f32_16x16x32_bf16(a[i], bb1, acc[i][3], 0, 0, 0);
    }
    __builtin_amdgcn_s_setprio(0);
    __builtin_amdgcn_s_barrier();
  }

  // Epilogue. C/D layout: col = lane&15, row = (lane>>4)*4 + reg [m89/m91].
  if (MODE == 0) {
    const bool is_delta = (n0 < H_DIM);  // block-uniform (gx=16, 8+8 split)
    const float* bias = is_delta ? bias0 : bias1;
    b16* ob = is_delta ? ob0 : ob1;
    const int nc0 = (n0 & (H_DIM - 1)) + wn * 64 + lm;
    float bv[4];
#pragma unroll
    for (int j = 0; j < 4; j++) bv[j] = bias[nc0 + j * 16];
#pragma unroll
    for (int i = 0; i < 8; i++) {
      const long rb = m0 + wm * 128 + i * 16 + l8 * 4;
      b16* pr = ob + rb * H_DIM + nc0;
      if (is_delta) {
#pragma unroll
        for (int j = 0; j < 4; j++)
#pragma unroll
          for (int rg = 0; rg < 4; ++rg)
            pr[(long)rg * H_DIM + j * 16] = (b16)softplus_fast(acc[i][j][rg] + bv[j]);
      } else {
#pragma unroll
        for (int j = 0; j < 4; j++)
#pragma unroll
          for (int rg = 0; rg < 4; ++rg)
            pr[(long)rg * H_DIM + j * 16] = (b16)(acc[i][j][rg] + bv[j]);
      }
    }
  } else if (MODE == 1) {
    const int nc0 = n0 + wn * 64 + lm;
#pragma unroll
    for (int i = 0; i < 8; i++) {
      const long rb = m0 + wm * 128 + i * 16 + l8 * 4;
      const b16* hp = hsel + rb * H_DIM + nc0;
      b16* pr = ob0 + rb * H_DIM + nc0;
#pragma unroll
      for (int j = 0; j < 4; j++)
#pragma unroll
        for (int rg = 0; rg < 4; ++rg) {
          float hv = (float)hp[(long)rg * H_DIM + j * 16];
          pr[(long)rg * H_DIM + j * 16] = (b16)(acc[i][j][rg] * hv);
        }
    }
  } else {
    const int nc0 = n0 + wn * 64 + lm;
    float bv[4];
#pragma unroll
    for (int j = 0; j < 4; j++) bv[j] = bias0[nc0 + j * 16];
#pragma unroll
    for (int i = 0; i < 8; i++) {
      const long rb = m0 + wm * 128 + i * 16 + l8 * 4;
      float* pr = of + rb * D_INP + nc0;
#pragma unroll
      for (int j = 0; j < 4; j++)
#pragma unroll
        for (int rg = 0; rg < 4; ++rg)
          pr[(long)rg * D_INP + j * 16] = acc[i][j][rg] + bv[j];
    }
  }
}

// ---------------------------------------------------------------------------
// Fallback: 128x128 kernel (used only if 128 KB dynamic LDS opt-in refused).
// ---------------------------------------------------------------------------
__device__ __forceinline__ int sw_off128(int r, int k8) {
  return r * 32 + ((k8 ^ ((r >> 1) & 3)) << 3);
}

template <int MODE>
__global__ __launch_bounds__(256, 2) void gemm_bt(
    const b16* __restrict__ A, const b16* __restrict__ W, int K,
    const float* __restrict__ bias0, const float* __restrict__ bias1,
    const b16* __restrict__ hsel, b16* __restrict__ ob0, b16* __restrict__ ob1,
    float* __restrict__ of) {
  __shared__ b16 As[128 * 32];
  __shared__ b16 Bs[128 * 32];
  const int tid  = threadIdx.x;
  const int lane = tid & 63;
  const int wave = tid >> 6;
  const int wr = wave >> 1, wc = wave & 1;
  const int m0 = blockIdx.y * 128;
  const int n0 = blockIdx.x * 128;
  const int lm = lane & 15;
  const int l8 = lane >> 4;
  const int rL  = wave * 16 + (lane >> 2);
  const int k8p = lane & 3;

  f32x4 acc[4][4];
#pragma unroll
  for (int i = 0; i < 4; i++)
#pragma unroll
    for (int j = 0; j < 4; j++) acc[i][j] = (f32x4)0.f;

  for (int k0 = 0; k0 < K; k0 += 32) {
#pragma unroll
    for (int hh = 0; hh < 2; ++hh) {
      const int r = rL + hh * 64;
      const int k8l = k8p ^ ((r >> 1) & 3);
      b16* ldsA = As + (wave * 16 + hh * 64) * 32;
      b16* ldsB = Bs + (wave * 16 + hh * 64) * 32;
      long arow = m0 + r;
      if (MODE == 1) arow = 2 * arow - (arow & 15) + 16;
      gl2lds16(A + arow * (long)K + k0 + k8l * 8, ldsA);
      gl2lds16(W + (long)(n0 + r) * K + k0 + k8l * 8, ldsB);
    }
    __syncthreads();
    b16x8 af[4], bfr[4];
#pragma unroll
    for (int i = 0; i < 4; i++) af[i] = *(const b16x8*)(As + sw_off128(wr * 64 + i * 16 + lm, l8));
#pragma unroll
    for (int j = 0; j < 4; j++) bfr[j] = *(const b16x8*)(Bs + sw_off128(wc * 64 + j * 16 + lm, l8));
#pragma unroll
    for (int i = 0; i < 4; i++)
#pragma unroll
      for (int j = 0; j < 4; j++)
        acc[i][j] = __builtin_amdgcn_mfma_f32_16x16x32_bf16(af[i], bfr[j], acc[i][j], 0, 0, 0);
    __syncthreads();
  }

  if (MODE == 0) {
    const bool is_delta = (n0 < H_DIM);
    const float* bias = is_delta ? bias0 : bias1;
    b16* ob = is_delta ? ob0 : ob1;
    const int nc0 = (n0 & (H_DIM - 1)) + wc * 64 + lm;
    float bv[4];
#pragma unroll
    for (int j = 0; j < 4; j++) bv[j] = bias[nc0 + j * 16];
#pragma unroll
    for (int i = 0; i < 4; i++) {
      const long rb = m0 + wr * 64 + i * 16 + l8 * 4;
      b16* pr = ob + rb * H_DIM + nc0;
      if (is_delta) {
#pragma unroll
        for (int j = 0; j < 4; j++)
#pragma unroll
          for (int rg = 0; rg < 4; ++rg)
            pr[(long)rg * H_DIM + j * 16] = (b16)softplus_fast(acc[i][j][rg] + bv[j]);
      } else {
#pragma unroll
        for (int j = 0; j < 4; j++)
#pragma unroll
          for (int rg = 0; rg < 4; ++rg)
            pr[(long)rg * H_DIM + j * 16] = (b16)(acc[i][j][rg] + bv[j]);
      }
    }
  } else if (MODE == 1) {
    const int nc0 = n0 + wc * 64 + lm;
#pragma unroll
    for (int i = 0; i < 4; i++) {
      const long rb = m0 + wr * 64 + i * 16 + l8 * 4;
      const b16* hp = hsel + rb * H_DIM + nc0;
      b16* pr = ob0 + rb * H_DIM + nc0;
#pragma unroll
      for (int j = 0; j < 4; j++)
#pragma unroll
        for (int rg = 0; rg < 4; ++rg) {
          float hv = (float)hp[(long)rg * H_DIM + j * 16];
          pr[(long)rg * H_DIM + j * 16] = (b16)(acc[i][j][rg] * hv);
        }
    }
  } else {
    const int nc0 = n0 + wc * 64 + lm;
    float bv[4];
#pragma unroll
    for (int j = 0; j < 4; j++) bv[j] = bias0[nc0 + j * 16];
#pragma unroll
    for (int i = 0; i < 4; i++) {
      const long rb = m0 + wr * 64 + i * 16 + l8 * 4;
      float* pr = of + rb * D_INP + nc0;
#pragma unroll
      for (int j = 0; j < 4; j++)
#pragma unroll
        for (int rg = 0; rg < 4; ++rg)
          pr[(long)rg * D_INP + j * 16] = acc[i][j][rg] + bv[j];
    }
  }
}

// ---------------------------------------------------------------------------
// Chunked-scan recurrence: h_t = (1-d_t) h_{t-1} + d_t u_t  (elementwise B*H)
// ---------------------------------------------------------------------------
__global__ void scan_a_kernel(const b16* __restrict__ dl, const b16* __restrict__ uu,
                              float* __restrict__ P, float* __restrict__ Q) {
  int g = blockIdx.x * 256 + threadIdx.x;
  int c = g >> 15;
  int p = g & (BH - 1);
  const b16* dp = dl + (size_t)c * CS * BH + p;
  const b16* up = uu + (size_t)c * CS * BH + p;
  float h = 0.f, pr = 1.f;
#pragma unroll 4
  for (int s = 0; s < CS; ++s) {
    float d = (float)dp[(size_t)s * BH];
    float u = (float)up[(size_t)s * BH];
    float a = 1.f - d;
    h = a * h + d * u;
    pr *= a;
  }
  P[g] = pr;
  Q[g] = h;
}

__global__ void scan_b_kernel(const float* __restrict__ P, const float* __restrict__ Q,
                              float* __restrict__ Hs) {
  int p = blockIdx.x * 256 + threadIdx.x;
  float h = 0.f;
#pragma unroll
  for (int c = 0; c < NC; ++c) {
    Hs[c * BH + p] = h;
    h = P[c * BH + p] * h + Q[c * BH + p];
  }
}

__global__ void scan_c_kernel(const b16* __restrict__ dl, const b16* __restrict__ uu,
                              const float* __restrict__ Hs, b16* __restrict__ hsel) {
  int g = blockIdx.x * 256 + threadIdx.x;
  int c = g >> 15;
  int p = g & (BH - 1);
  const b16* dp = dl + (size_t)c * CS * BH + p;
  const b16* up = uu + (size_t)c * CS * BH + p;
  b16* hp = hsel + (size_t)(c * (CS / 2)) * BH + p;
  float h = Hs[g];
#pragma unroll 4
  for (int s = 0; s < CS; ++s) {
    float d = (float)dp[(size_t)s * BH];
    float u = (float)up[(size_t)s * BH];
    h = (1.f - d) * h + d * u;
    if (s & 1) hp[(size_t)(s >> 1) * BH] = (b16)h;
  }
}

// ---------------------------------------------------------------------------
extern "C" void kernel_launch(void* const* d_in, const int* in_sizes, int n_in,
                              void* d_out, int out_size, void* d_ws, size_t ws_size,
                              hipStream_t stream) {
  const float* x   = (const float*)d_in[0];
  // d_in[1] = A (unused by the reference forward)
  const float* WB  = (const float*)d_in[2];
  const float* Wc  = (const float*)d_in[3];
  const float* Wd  = (const float*)d_in[4];
  const float* bd  = (const float*)d_in[5];
  const float* Win = (const float*)d_in[6];
  const float* bi  = (const float*)d_in[7];
  const float* Wcp = (const float*)d_in[8];
  const float* bc  = (const float*)d_in[9];
  float* out = (float*)d_out;

  char* w = (char*)d_ws;
  size_t off = 0;
  auto alloc = [&](size_t bytes) {
    void* p = w + off;
    off += (bytes + 255) & ~(size_t)255;
    return p;
  };
  b16* xb   = (b16*)alloc((size_t)S_LEN * BATCH * D_INP * 2);
  b16* Wdu  = (b16*)alloc((size_t)2 * H_DIM * D_INP * 2);
  b16* Wcb  = (b16*)alloc((size_t)H_DIM * D_INP * 2);
  b16* Wcpb = (b16*)alloc((size_t)D_INP * H_DIM * 2);
  b16* dbuf = (b16*)alloc((size_t)S_LEN * BH * 2);
  b16* ubuf = (b16*)alloc((size_t)S_LEN * BH * 2);
  b16* hsel = (b16*)alloc((size_t)SC * BH * 2);
  b16* ysel = (b16*)alloc((size_t)SC * BH * 2);
  float* P  = (float*)alloc((size_t)NC * BH * 4);
  float* Q  = (float*)alloc((size_t)NC * BH * 4);
  float* Hs = (float*)alloc((size_t)NC * BH * 4);
  if (off > ws_size) {
    fprintf(stderr, "kernel_launch: ws too small: need %zu have %zu\n", off, ws_size);
    return;
  }

  // One-time opt-in to 128 KB dynamic LDS for the 8-phase kernels.
  static int g_big = -1;
  if (g_big < 0) {
    hipError_t e0 = hipFuncSetAttribute(reinterpret_cast<const void*>(&gemm8p<0>),
                                        hipFuncAttributeMaxDynamicSharedMemorySize, 131072);
    hipError_t e1 = hipFuncSetAttribute(reinterpret_cast<const void*>(&gemm8p<1>),
                                        hipFuncAttributeMaxDynamicSharedMemorySize, 131072);
    hipError_t e2 = hipFuncSetAttribute(reinterpret_cast<const void*>(&gemm8p<2>),
                                        hipFuncAttributeMaxDynamicSharedMemorySize, 131072);
    g_big = (e0 == hipSuccess && e1 == hipSuccess && e2 == hipSuccess) ? 1 : 0;
  }

  // 1) x -> bf16
  int n4 = S_LEN * BATCH * D_INP / 4;
  cvt_x_kernel<<<(n4 + 255) / 256, 256, 0, stream>>>(x, xb, n4);
  // 2) weights -> bf16 (+ W_in+W_B fold)
  int hd4 = H_DIM * D_INP / 4;
  prep_w_kernel<<<(hd4 + 255) / 256, 256, 0, stream>>>(Wd, Win, WB, Wc, Wcp, Wdu, Wcb, Wcpb);
  // 3) delta/u projections: M=32768, N=4096, K=1024
  if (g_big) {
    dim3 g1(2 * H_DIM / 256, S_LEN * BATCH / 256);  // 16 x 128 = 2048 blocks
    gemm8p<0><<<g1, 512, 131072, stream>>>(xb, Wdu, D_INP, bd, bi, nullptr, dbuf, ubuf, nullptr);
  } else {
    dim3 g1(2 * H_DIM / 128, S_LEN * BATCH / 128);
    gemm_bt<0><<<g1, 256, 0, stream>>>(xb, Wdu, D_INP, bd, bi, nullptr, dbuf, ubuf, nullptr);
  }
  // 4-6) chunked scan over S
  scan_a_kernel<<<NC * BH / 256, 256, 0, stream>>>(dbuf, ubuf, P, Q);
  scan_b_kernel<<<BH / 256, 256, 0, stream>>>(P, Q, Hs);
  scan_c_kernel<<<NC * BH / 256, 256, 0, stream>>>(dbuf, ubuf, Hs, hsel);
  // 7) C projection at odd timesteps, fused *h: M=16384, N=2048, K=1024
  if (g_big) {
    dim3 g2(H_DIM / 256, SC * BATCH / 256);  // 8 x 64 = 512 blocks
    gemm8p<1><<<g2, 512, 131072, stream>>>(xb, Wcb, D_INP, nullptr, nullptr, hsel, ysel, nullptr, nullptr);
  } else {
    dim3 g2(H_DIM / 128, SC * BATCH / 128);
    gemm_bt<1><<<g2, 256, 0, stream>>>(xb, Wcb, D_INP, nullptr, nullptr, hsel, ysel, nullptr, nullptr);
  }
  // 8) compress: M=16384, N=1024, K=2048, fp32 out + b_comp
  if (g_big) {
    dim3 g3(D_INP / 256, SC * BATCH / 256);  // 4 x 64 = 256 blocks
    gemm8p<2><<<g3, 512, 131072, stream>>>(ysel, Wcpb, H_DIM, bc, nullptr, nullptr, nullptr, nullptr, out);
  } else {
    dim3 g3(D_INP / 128, SC * BATCH / 128);
    gemm_bt<2><<<g3, 256, 0, stream>>>(ysel, Wcpb, H_DIM, bc, nullptr, nullptr, nullptr, nullptr, out);
  }
}